// Round 1
// baseline (66.897 us; speedup 1.0000x reference)
//
#include <hip/hip_runtime.h>
#include <stdint.h>

// ChunkMasker: mask is input-independent (jax.random.key(1)).
// Pipeline: [rng_kernel] packed (start,len) per attempt -> d_out tail (scratch)
//           [scan_kernel] sequential span-OR scan w/ early exit -> bitset in d_ws
//           [apply_kernel] masked_x + float mask tail -> d_out
// RNG semantics: JAX threefry2x32 with jax_threefry_partitionable=True
// (fold-like split: child_i = cipher(key,(0,i)); bits[f] = xor-fold of
// cipher(key,(0,f))). Fallback if this fails: original (pre-partitionable)
// path pairs counters (f, f+N/2) and uses out-halves concatenated.

#define B_ 32
#define T_ 1500
#define D_ 768
#define G_ 1500            // guard budget = 4 * num_to_mask
#define NUM_TO_MASK 375
#define NWORDS 47          // ceil(1500/32)
#define NX (B_*T_*D_)      // 36864000
#define NX4 (NX/4)         // 9216000
#define NMASK (B_*T_)      // 48000
#define NMASK4 (NMASK/4)   // 12000

__host__ __device__ static inline void tf2x32(uint32_t ka, uint32_t kb,
                                              uint32_t x0, uint32_t x1,
                                              uint32_t &o0, uint32_t &o1) {
  uint32_t kc = ka ^ kb ^ 0x1BD11BDAu;
#define TFR(r) { x0 += x1; x1 = ((x1 << (r)) | (x1 >> (32 - (r)))); x1 ^= x0; }
  x0 += ka; x1 += kb;
  TFR(13) TFR(15) TFR(26) TFR(6)   x0 += kb; x1 += kc + 1u;
  TFR(17) TFR(29) TFR(16) TFR(24)  x0 += kc; x1 += ka + 2u;
  TFR(13) TFR(15) TFR(26) TFR(6)   x0 += ka; x1 += kb + 3u;
  TFR(17) TFR(29) TFR(16) TFR(24)  x0 += kb; x1 += kc + 4u;
  TFR(13) TFR(15) TFR(26) TFR(6)   x0 += kc; x1 += ka + 5u;
#undef TFR
  o0 = x0; o1 = x1;
}

// One thread per attempt element f = g*32 + b. Three ciphers:
// lens lower bits (span=4 -> multiplier=0, higher bits unused),
// starts higher bits, starts lower bits.
__global__ void __launch_bounds__(256)
rng_kernel(uint32_t* __restrict__ packed,
           uint32_t k1b0, uint32_t k1b1,
           uint32_t k2a0, uint32_t k2a1,
           uint32_t k2b0, uint32_t k2b1) {
  const int f = blockIdx.x * 256 + threadIdx.x;
  if (f >= G_ * B_) return;
  uint32_t a, b;
  tf2x32(k1b0, k1b1, 0u, (uint32_t)f, a, b);
  const uint32_t len = 2u + ((a ^ b) & 3u);           // randint [2,6)
  tf2x32(k2a0, k2a1, 0u, (uint32_t)f, a, b);
  const uint32_t hi = a ^ b;
  tf2x32(k2b0, k2b1, 0u, (uint32_t)f, a, b);
  const uint32_t lo = a ^ b;
  const uint32_t span = (uint32_t)T_ - len;           // maxval = 1500-len > 0
  uint32_t m = 65536u % span;
  m = (m * m) % span;
  const uint32_t off = ((hi % span) * m + (lo % span)) % span;
  packed[f] = (off << 2) | (len - 2u);
}

// One block (one wave) per batch element. Lane l owns bitset word l.
// Per step: broadcast packed attempt via readlane (uniform/scalar control
// flow), OR span bits into owned word, gather popcount delta from the 1-2
// touched lanes via readlane, early-exit once count >= 375 (matches the
// reference's done-gating: the crossing span IS applied, later ones are not).
__global__ void __launch_bounds__(64)
scan_kernel(const uint32_t* __restrict__ packed, uint32_t* __restrict__ bits) {
  const int b = blockIdx.x;
  const int l = threadIdx.x;
  uint32_t word = 0u;
  int count = 0;
  bool done = false;
  for (int chunk = 0; chunk < (G_ + 63) / 64 && !done; ++chunk) {
    const int gbase = chunk * 64;
    const int gl = gbase + l;
    uint32_t vp = 0u;
    if (gl < G_) vp = packed[gl * B_ + b];     // lane l prefetches step gbase+l
    const int nsteps = (G_ - gbase) < 64 ? (G_ - gbase) : 64;
    for (int j = 0; j < nsteps; ++j) {
      const uint32_t pk = (uint32_t)__builtin_amdgcn_readlane((int)vp, j);
      const int len = (int)(pk & 3u) + 2;
      const int start = (int)(pk >> 2);
      const int end = start + len;             // exclusive, <= 1500
      int lo = start - 32 * l;
      int hi = end - 32 * l;
      lo = lo < 0 ? 0 : lo;
      hi = hi > 32 ? 32 : hi;
      uint32_t mb = 0u;
      if (hi > lo) mb = ((1u << (hi - lo)) - 1u) << lo;  // hi-lo <= 5
      const int delta = __popc(mb & ~word);
      word |= mb;
      const int w0 = start >> 5;
      const int w1 = (end - 1) >> 5;
      int d = __builtin_amdgcn_readlane(delta, w0);
      if (w1 != w0) d += __builtin_amdgcn_readlane(delta, w1);
      count += d;
      if (count >= NUM_TO_MASK) { done = true; break; }
    }
  }
  if (l < NWORDS) bits[b * NWORDS + l] = word;
}

// Streaming apply: float4 per thread. First NX4 threads: masked_x.
// Next NMASK4 threads: float mask tail (overwrites the packed scratch).
__global__ void __launch_bounds__(256)
apply_kernel(const float4* __restrict__ x4, float4* __restrict__ out4,
             const uint32_t* __restrict__ bits) {
  const int idx = blockIdx.x * 256 + threadIdx.x;
  if (idx < NX4) {
    const int bt = idx / (D_ / 4);            // /192 -> b*1500+t
    const int b = bt / T_;
    const int t = bt - b * T_;
    const uint32_t w = bits[b * NWORDS + (t >> 5)];
    float4 v = x4[idx];
    if ((w >> (t & 31)) & 1u) v = make_float4(0.f, 0.f, 0.f, 0.f);
    out4[idx] = v;
  } else if (idx < NX4 + NMASK4) {
    const int f4 = idx - NX4;
    const int f0 = f4 * 4;                    // b*1500 + t0, t0 % 4 == 0
    const int b = f0 / T_;
    const int t0 = f0 - b * T_;
    const uint32_t w = bits[b * NWORDS + (t0 >> 5)];  // t0&31 <= 28: one word
    float4 v;
    v.x = ((w >> ((t0 + 0) & 31)) & 1u) ? 1.f : 0.f;
    v.y = ((w >> ((t0 + 1) & 31)) & 1u) ? 1.f : 0.f;
    v.z = ((w >> ((t0 + 2) & 31)) & 1u) ? 1.f : 0.f;
    v.w = ((w >> ((t0 + 3) & 31)) & 1u) ? 1.f : 0.f;
    out4[idx] = v;
  }
}

extern "C" void kernel_launch(void* const* d_in, const int* in_sizes, int n_in,
                              void* d_out, int out_size, void* d_ws, size_t ws_size,
                              hipStream_t stream) {
  const float* x = (const float*)d_in[0];
  float* out = (float*)d_out;
  // Scratch: packed attempts live in the d_out mask-tail region (48000 u32 ==
  // exactly the 48000-float tail); bitset (6016 B) in d_ws. Kernels are
  // stream-ordered, apply overwrites the tail last.
  uint32_t* packed = (uint32_t*)out + NX;
  uint32_t* bits = (uint32_t*)d_ws;

  // Host-side key derivation (partitionable fold-like split):
  // root = key(1) = (0,1)
  // k1 = cipher(root,(0,0)), k2 = cipher(root,(0,1))      [top-level split]
  // lens  = randint(k1,...): k1b = cipher(k1,(0,1))  (k1a unused: span=4)
  // starts= randint(k2,...): k2a = cipher(k2,(0,0)), k2b = cipher(k2,(0,1))
  uint32_t k1_0, k1_1, k2_0, k2_1;
  tf2x32(0u, 1u, 0u, 0u, k1_0, k1_1);
  tf2x32(0u, 1u, 0u, 1u, k2_0, k2_1);
  uint32_t k1b0, k1b1, k2a0, k2a1, k2b0, k2b1;
  tf2x32(k1_0, k1_1, 0u, 1u, k1b0, k1b1);
  tf2x32(k2_0, k2_1, 0u, 0u, k2a0, k2a1);
  tf2x32(k2_0, k2_1, 0u, 1u, k2b0, k2b1);

  hipLaunchKernelGGL(rng_kernel, dim3((G_ * B_ + 255) / 256), dim3(256), 0, stream,
                     packed, k1b0, k1b1, k2a0, k2a1, k2b0, k2b1);
  hipLaunchKernelGGL(scan_kernel, dim3(B_), dim3(64), 0, stream, packed, bits);
  hipLaunchKernelGGL(apply_kernel, dim3((NX4 + NMASK4 + 255) / 256), dim3(256), 0,
                     stream, (const float4*)x, (float4*)out, bits);
}

// Round 2
// 52.544 us; speedup vs baseline: 1.2732x; 1.2732x over previous
//
#include <hip/hip_runtime.h>
#include <stdint.h>

// ChunkMasker: mask is input-independent (jax.random.key(1)), verified
// bit-exact (absmax 0) in R0 with jax_threefry_partitionable semantics.
// R1: fuse rng into scan (no packed round-trip); replace the serial
// readlane scan with order-independent chunk-union + binary search
// (mask after g attempts == union of spans 0..g, so the crossing attempt
// is found by monotone popcount search); skip x loads on masked frames.

#define B_ 32
#define T_ 1500
#define D_ 768
#define G_ 1500            // guard budget = 4 * num_to_mask
#define NUM_TO_MASK 375
#define NWORDS 47          // ceil(1500/32)
#define NCHUNK ((G_ + 63) / 64)
#define NX (B_*T_*D_)      // 36864000
#define NX4 (NX/4)         // 9216000
#define NMASK (B_*T_)      // 48000
#define NMASK4 (NMASK/4)   // 12000

typedef float f4 __attribute__((ext_vector_type(4)));

__host__ __device__ static inline void tf2x32(uint32_t ka, uint32_t kb,
                                              uint32_t x0, uint32_t x1,
                                              uint32_t &o0, uint32_t &o1) {
  uint32_t kc = ka ^ kb ^ 0x1BD11BDAu;
#define TFR(r) { x0 += x1; x1 = ((x1 << (r)) | (x1 >> (32 - (r)))); x1 ^= x0; }
  x0 += ka; x1 += kb;
  TFR(13) TFR(15) TFR(26) TFR(6)   x0 += kb; x1 += kc + 1u;
  TFR(17) TFR(29) TFR(16) TFR(24)  x0 += kc; x1 += ka + 2u;
  TFR(13) TFR(15) TFR(26) TFR(6)   x0 += ka; x1 += kb + 3u;
  TFR(17) TFR(29) TFR(16) TFR(24)  x0 += kb; x1 += kc + 4u;
  TFR(13) TFR(15) TFR(26) TFR(6)   x0 += kc; x1 += ka + 5u;
#undef TFR
  o0 = x0; o1 = x1;
}

__device__ static inline int wave_sum64(int v) {
  for (int s = 1; s < 64; s <<= 1) v += __shfl_xor(v, s);
  return v;
}

// One block (one wave) per batch element. Fused RNG + order-independent scan.
// Per 64-attempt chunk: lane j computes attempt g=chunk*64+j (3 ciphers),
// its span bits (1-2 words). Whole-chunk trial union via LDS atomicOr +
// popcount reduce; if it crosses NUM_TO_MASK, binary-search the smallest
// prefix k with popcount(u ∪ spans[0..k]) >= NUM_TO_MASK (monotone), apply
// spans 0..k, done. Matches reference gating exactly (crossing span applied,
// later spans not).
__global__ void __launch_bounds__(64)
scan_kernel(uint32_t* __restrict__ bits,
            uint32_t k1b0, uint32_t k1b1,
            uint32_t k2a0, uint32_t k2a1,
            uint32_t k2b0, uint32_t k2b1) {
  const int b = blockIdx.x;
  const int l = threadIdx.x;
  __shared__ uint32_t u[NWORDS];   // committed union
  __shared__ uint32_t t[NWORDS];   // trial union
  if (l < NWORDS) u[l] = 0u;
  __syncthreads();
  bool done = false;
  for (int chunk = 0; chunk < NCHUNK && !done; ++chunk) {
    const int g = chunk * 64 + l;
    const bool valid = (g < G_);
    uint32_t m0 = 0u, m1 = 0u;
    int w0 = 0, w1 = 0;
    if (valid) {
      const uint32_t f = (uint32_t)(g * B_ + b);
      uint32_t a0, a1;
      tf2x32(k1b0, k1b1, 0u, f, a0, a1);
      const uint32_t len = 2u + ((a0 ^ a1) & 3u);      // randint [2,6)
      tf2x32(k2a0, k2a1, 0u, f, a0, a1);
      const uint32_t hb = a0 ^ a1;
      tf2x32(k2b0, k2b1, 0u, f, a0, a1);
      const uint32_t lb = a0 ^ a1;
      const uint32_t span = (uint32_t)T_ - len;
      uint32_t mm = 65536u % span;
      mm = (mm * mm) % span;
      const uint32_t start = ((hb % span) * mm + (lb % span)) % span;
      const uint32_t end = start + len;                // <= 1500
      w0 = (int)(start >> 5);
      w1 = (int)((end - 1u) >> 5);
      const int sh = (int)(start & 31u);
      const int n0 = min((int)len, 32 - sh);           // 1..5
      m0 = ((1u << n0) - 1u) << sh;
      if (w1 != w0) m1 = (1u << ((int)len - n0)) - 1u;
    }
    // whole-chunk trial
    if (l < NWORDS) t[l] = u[l];
    __syncthreads();
    if (valid) { atomicOr(&t[w0], m0); if (w1 != w0) atomicOr(&t[w1], m1); }
    __syncthreads();
    int tot = wave_sum64((l < NWORDS) ? __popc(t[l]) : 0);
    if (tot < NUM_TO_MASK) {
      __syncthreads();
      if (l < NWORDS) u[l] = t[l];
      __syncthreads();
      continue;
    }
    // crossing inside this chunk: binary search smallest k
    int lo = 0;
    int hi = min(63, G_ - chunk * 64 - 1);
    while (lo < hi) {
      const int mid = (lo + hi) >> 1;
      __syncthreads();
      if (l < NWORDS) t[l] = u[l];
      __syncthreads();
      if (valid && l <= mid) { atomicOr(&t[w0], m0); if (w1 != w0) atomicOr(&t[w1], m1); }
      __syncthreads();
      tot = wave_sum64((l < NWORDS) ? __popc(t[l]) : 0);
      if (tot >= NUM_TO_MASK) hi = mid; else lo = mid + 1;
    }
    // commit spans 0..lo
    __syncthreads();
    if (l < NWORDS) t[l] = u[l];
    __syncthreads();
    if (valid && l <= lo) { atomicOr(&t[w0], m0); if (w1 != w0) atomicOr(&t[w1], m1); }
    __syncthreads();
    if (l < NWORDS) u[l] = t[l];
    done = true;
  }
  __syncthreads();
  if (l < NWORDS) bits[b * NWORDS + l] = u[l];
}

// Streaming apply: float4 per thread. Masked frames skip the x load
// (spans are contiguous -> mostly wave-uniform predicate -> exec=0 skips
// the fetch). Tail threads write the float mask.
__global__ void __launch_bounds__(256)
apply_kernel(const f4* __restrict__ x4, f4* __restrict__ out4,
             const uint32_t* __restrict__ bits) {
  const int idx = blockIdx.x * 256 + threadIdx.x;
  if (idx < NX4) {
    const int bt = idx / (D_ / 4);            // /192 -> b*1500+t
    const int b = bt / T_;
    const int t = bt - b * T_;
    const uint32_t w = bits[b * NWORDS + (t >> 5)];
    f4 v = (f4)(0.f);
    if (!((w >> (t & 31)) & 1u)) v = __builtin_nontemporal_load(&x4[idx]);
    __builtin_nontemporal_store(v, &out4[idx]);
  } else if (idx < NX4 + NMASK4) {
    const int f4i = idx - NX4;
    const int f0 = f4i * 4;                   // b*1500 + t0, t0 % 4 == 0
    const int b = f0 / T_;
    const int t0 = f0 - b * T_;
    const uint32_t w = bits[b * NWORDS + (t0 >> 5)];  // t0&31 <= 28: one word
    f4 v;
    v.x = ((w >> ((t0 + 0) & 31)) & 1u) ? 1.f : 0.f;
    v.y = ((w >> ((t0 + 1) & 31)) & 1u) ? 1.f : 0.f;
    v.z = ((w >> ((t0 + 2) & 31)) & 1u) ? 1.f : 0.f;
    v.w = ((w >> ((t0 + 3) & 31)) & 1u) ? 1.f : 0.f;
    __builtin_nontemporal_store(v, &out4[idx]);
  }
}

extern "C" void kernel_launch(void* const* d_in, const int* in_sizes, int n_in,
                              void* d_out, int out_size, void* d_ws, size_t ws_size,
                              hipStream_t stream) {
  const float* x = (const float*)d_in[0];
  float* out = (float*)d_out;
  uint32_t* bits = (uint32_t*)d_ws;           // 6016 B

  // Host-side key derivation (partitionable fold-like split), verified R0:
  // root = key(1) = (0,1)
  // k1 = cipher(root,(0,0)), k2 = cipher(root,(0,1))
  // lens  : k1b = cipher(k1,(0,1))   (k1a unused: span=4 -> multiplier 0)
  // starts: k2a = cipher(k2,(0,0)), k2b = cipher(k2,(0,1))
  uint32_t k1_0, k1_1, k2_0, k2_1;
  tf2x32(0u, 1u, 0u, 0u, k1_0, k1_1);
  tf2x32(0u, 1u, 0u, 1u, k2_0, k2_1);
  uint32_t k1b0, k1b1, k2a0, k2a1, k2b0, k2b1;
  tf2x32(k1_0, k1_1, 0u, 1u, k1b0, k1b1);
  tf2x32(k2_0, k2_1, 0u, 0u, k2a0, k2a1);
  tf2x32(k2_0, k2_1, 0u, 1u, k2b0, k2b1);

  hipLaunchKernelGGL(scan_kernel, dim3(B_), dim3(64), 0, stream,
                     bits, k1b0, k1b1, k2a0, k2a1, k2b0, k2b1);
  hipLaunchKernelGGL(apply_kernel, dim3((NX4 + NMASK4 + 255) / 256), dim3(256), 0,
                     stream, (const f4*)x, (f4*)out, bits);
}